// Round 1
// baseline (2541.955 us; speedup 1.0000x reference)
//
#include <hip/hip_runtime.h>

#define HID 128
#define NOUT 40

// ---------------- edge dtype detect + convert ----------------
// If edge_index is int64 (little-endian, values < 2^31), every odd 32-bit
// word is 0. If int32, odd words are random node ids in [0, 50000) -> the
// probability all 64 are zero is ~0.
__global__ void detect_fmt_kernel(const unsigned int* __restrict__ e, int* __restrict__ flag) {
    int t = threadIdx.x;  // 64 threads, one wave
    unsigned int v = e[2 * t + 1];
    unsigned long long ball = __ballot(v == 0u);
    if (t == 0) *flag = (ball == ~0ull) ? 1 : 0;
}

__global__ void convert_kernel(const void* __restrict__ eix, const int* __restrict__ flag,
                               int* __restrict__ rc, int n2e) {
    int i = blockIdx.x * blockDim.x + threadIdx.x;
    if (i >= n2e) return;
    int f = *flag;
    int v;
    if (f) v = (int)(((const long long*)eix)[i]);
    else   v = ((const int*)eix)[i];
    rc[i] = v;
}

__global__ void degree_kernel(const int* __restrict__ col, int* __restrict__ deg, int E) {
    int i = blockIdx.x * blockDim.x + threadIdx.x;
    if (i < E) atomicAdd(&deg[col[i]], 1);
}

__global__ void dinv_kernel(const int* __restrict__ deg, float* __restrict__ dinv, int n) {
    int i = blockIdx.x * blockDim.x + threadIdx.x;
    if (i < n) dinv[i] = rsqrtf((float)deg[i] + 1.0f);  // +1 = self loop
}

// ---------------- fp32 GEMM: C[M,128] = A[M,K] @ B[K,128] ----------------
// 64x128 block tile, 256 threads, 4x8 per-thread micro-tile, BK=32.
__global__ __launch_bounds__(256) void gemm128_kernel(
    const float* __restrict__ A, const float* __restrict__ B,
    float* __restrict__ C, int M, int K) {
    __shared__ float As[32][68];   // [k][m], padded
    __shared__ float Bs[32][132];  // [k][h], padded
    const int tid = threadIdx.x;
    const int tx = tid & 15;
    const int ty = tid >> 4;
    const int bm = blockIdx.x * 64;

    float acc[4][8];
#pragma unroll
    for (int i = 0; i < 4; ++i)
#pragma unroll
        for (int j = 0; j < 8; ++j) acc[i][j] = 0.f;

    const int kk = tid & 31;
    const int am = tid >> 5;
    const int bh = tid & 127;
    const int bk = tid >> 7;

    for (int k0 = 0; k0 < K; k0 += 32) {
#pragma unroll
        for (int p = 0; p < 8; ++p) {
            int m = am + p * 8;
            int gr = bm + m;
            As[kk][m] = (gr < M) ? A[(size_t)gr * K + (k0 + kk)] : 0.f;
        }
#pragma unroll
        for (int p = 0; p < 16; ++p) {
            int r = bk + p * 2;
            Bs[r][bh] = B[(size_t)(k0 + r) * HID + bh];
        }
        __syncthreads();
#pragma unroll
        for (int k = 0; k < 32; ++k) {
            float a0 = As[k][ty * 4 + 0];
            float a1 = As[k][ty * 4 + 1];
            float a2 = As[k][ty * 4 + 2];
            float a3 = As[k][ty * 4 + 3];
            float b0 = Bs[k][tx * 8 + 0];
            float b1 = Bs[k][tx * 8 + 1];
            float b2 = Bs[k][tx * 8 + 2];
            float b3 = Bs[k][tx * 8 + 3];
            float b4 = Bs[k][tx * 8 + 4];
            float b5 = Bs[k][tx * 8 + 5];
            float b6 = Bs[k][tx * 8 + 6];
            float b7 = Bs[k][tx * 8 + 7];
            acc[0][0] += a0 * b0; acc[0][1] += a0 * b1; acc[0][2] += a0 * b2; acc[0][3] += a0 * b3;
            acc[0][4] += a0 * b4; acc[0][5] += a0 * b5; acc[0][6] += a0 * b6; acc[0][7] += a0 * b7;
            acc[1][0] += a1 * b0; acc[1][1] += a1 * b1; acc[1][2] += a1 * b2; acc[1][3] += a1 * b3;
            acc[1][4] += a1 * b4; acc[1][5] += a1 * b5; acc[1][6] += a1 * b6; acc[1][7] += a1 * b7;
            acc[2][0] += a2 * b0; acc[2][1] += a2 * b1; acc[2][2] += a2 * b2; acc[2][3] += a2 * b3;
            acc[2][4] += a2 * b4; acc[2][5] += a2 * b5; acc[2][6] += a2 * b6; acc[2][7] += a2 * b7;
            acc[3][0] += a3 * b0; acc[3][1] += a3 * b1; acc[3][2] += a3 * b2; acc[3][3] += a3 * b3;
            acc[3][4] += a3 * b4; acc[3][5] += a3 * b5; acc[3][6] += a3 * b6; acc[3][7] += a3 * b7;
        }
        __syncthreads();
    }

#pragma unroll
    for (int i = 0; i < 4; ++i) {
        int gr = bm + ty * 4 + i;
        if (gr < M) {
            float4* cp = (float4*)(C + (size_t)gr * HID + tx * 8);
            cp[0] = make_float4(acc[i][0], acc[i][1], acc[i][2], acc[i][3]);
            cp[1] = make_float4(acc[i][4], acc[i][5], acc[i][6], acc[i][7]);
        }
    }
}

// x_out = h * dinv^2 + bias   (self-loop term + bias, before edge scatter)
__global__ void preset_kernel(const float* __restrict__ h, const float* __restrict__ dinv,
                              const float* __restrict__ bias, float* __restrict__ xo, int n128) {
    int i = blockIdx.x * blockDim.x + threadIdx.x;
    if (i >= n128) return;
    int n = i >> 7;
    int j = i & 127;
    float d = dinv[n];
    xo[i] = h[i] * d * d + bias[j];
}

// one wave per edge (grid-stride): xo[col] += h[row] * dinv[row]*dinv[col]
__global__ __launch_bounds__(256) void aggregate_kernel(
    const float* __restrict__ h, const int* __restrict__ row, const int* __restrict__ col,
    const float* __restrict__ dinv, float* __restrict__ xo, int E) {
    const int lane = threadIdx.x & 63;
    int wid = (blockIdx.x * blockDim.x + threadIdx.x) >> 6;
    const int nw = (gridDim.x * blockDim.x) >> 6;
    const float2* h2 = (const float2*)h;
    for (int e = wid; e < E; e += nw) {
        int r = row[e];
        int c = col[e];
        float nrm = dinv[r] * dinv[c];
        float2 v = h2[(size_t)r * 64 + lane];
        atomicAdd(&xo[(size_t)c * 128 + lane * 2 + 0], v.x * nrm);
        atomicAdd(&xo[(size_t)c * 128 + lane * 2 + 1], v.y * nrm);
    }
}

__global__ void relu_kernel(float* __restrict__ x, int n) {
    int i = blockIdx.x * blockDim.x + threadIdx.x;
    if (i < n) x[i] = fmaxf(x[i], 0.f);
}

// out[n,o] = sum_k x1[n,k]W[k,o] + x2[n,k]W[128+k,o] + x3[n,k]W[256+k,o] + bout[o]
// block = 4 rows x 64 cols (40 valid), Wout staged in LDS.
__global__ __launch_bounds__(256) void out_gemm_kernel(
    const float* __restrict__ x1, const float* __restrict__ x2, const float* __restrict__ x3,
    const float* __restrict__ Wout, const float* __restrict__ bout,
    float* __restrict__ out, int M) {
    __shared__ float Ws[384 * NOUT];  // 61.4 KB
    const int tid = threadIdx.x;
    for (int i = tid; i < 384 * NOUT; i += 256) Ws[i] = Wout[i];
    __syncthreads();

    const int o = tid & 63;
    const int oe = (o < NOUT) ? o : (NOUT - 1);
    const int n = blockIdx.x * 4 + (tid >> 6);
    if (n >= M) return;

    float acc = bout[oe];
    const float* xs[3] = {x1, x2, x3};
#pragma unroll
    for (int s = 0; s < 3; ++s) {
        const float4* xp = (const float4*)(xs[s] + (size_t)n * HID);
        const float* Wp = Ws + s * HID * NOUT;
#pragma unroll 4
        for (int k4 = 0; k4 < 32; ++k4) {
            float4 v = xp[k4];
            acc += v.x * Wp[(k4 * 4 + 0) * NOUT + oe];
            acc += v.y * Wp[(k4 * 4 + 1) * NOUT + oe];
            acc += v.z * Wp[(k4 * 4 + 2) * NOUT + oe];
            acc += v.w * Wp[(k4 * 4 + 3) * NOUT + oe];
        }
    }
    if (o < NOUT) out[(size_t)n * NOUT + o] = acc;
}

// ---------------- launch ----------------
static inline size_t align_up(size_t x, size_t a) { return (x + a - 1) / a * a; }

extern "C" void kernel_launch(void* const* d_in, const int* in_sizes, int n_in,
                              void* d_out, int out_size, void* d_ws, size_t ws_size,
                              hipStream_t stream) {
    const float* x    = (const float*)d_in[0];
    const void*  eix  = d_in[1];
    const float* W0   = (const float*)d_in[2];
    const float* b0   = (const float*)d_in[3];
    const float* W1   = (const float*)d_in[4];
    const float* b1   = (const float*)d_in[5];
    const float* W2   = (const float*)d_in[6];
    const float* b2   = (const float*)d_in[7];
    const float* Wout = (const float*)d_in[8];
    const float* bout = (const float*)d_in[9];
    float* out = (float*)d_out;

    const int D = 256;
    const int N = in_sizes[0] / D;        // 50000
    const int E = in_sizes[1] / 2;        // 800000

    // workspace carve-out
    char* w = (char*)d_ws;
    size_t off = 0;
    int* rc = (int*)(w + off);            off = align_up(off + (size_t)2 * E * 4, 256);
    int* deg = (int*)(w + off);           off = align_up(off + (size_t)N * 4, 256);
    float* dinv = (float*)(w + off);      off = align_up(off + (size_t)N * 4, 256);
    int* flag = (int*)(w + off);          off = align_up(off + 16, 256);
    float* h  = (float*)(w + off);        off = align_up(off + (size_t)N * HID * 4, 256);
    float* x1 = (float*)(w + off);        off = align_up(off + (size_t)N * HID * 4, 256);
    float* x2 = (float*)(w + off);        off = align_up(off + (size_t)N * HID * 4, 256);
    float* x3 = (float*)(w + off);        off = align_up(off + (size_t)N * HID * 4, 256);
    (void)ws_size;

    int* row = rc;
    int* col = rc + E;

    // graph prep
    detect_fmt_kernel<<<1, 64, 0, stream>>>((const unsigned int*)eix, flag);
    convert_kernel<<<(2 * E + 255) / 256, 256, 0, stream>>>(eix, flag, rc, 2 * E);
    hipMemsetAsync(deg, 0, (size_t)N * 4, stream);
    degree_kernel<<<(E + 255) / 256, 256, 0, stream>>>(col, deg, E);
    dinv_kernel<<<(N + 255) / 256, 256, 0, stream>>>(deg, dinv, N);

    const int n128 = N * HID;
    const int gElem = (n128 + 255) / 256;
    const int gGemm = (N + 63) / 64;

    // layer 0
    gemm128_kernel<<<gGemm, 256, 0, stream>>>(x, W0, h, N, 256);
    preset_kernel<<<gElem, 256, 0, stream>>>(h, dinv, b0, x1, n128);
    aggregate_kernel<<<4096, 256, 0, stream>>>(h, row, col, dinv, x1, E);
    relu_kernel<<<gElem, 256, 0, stream>>>(x1, n128);
    // layer 1
    gemm128_kernel<<<gGemm, 256, 0, stream>>>(x1, W1, h, N, 128);
    preset_kernel<<<gElem, 256, 0, stream>>>(h, dinv, b1, x2, n128);
    aggregate_kernel<<<4096, 256, 0, stream>>>(h, row, col, dinv, x2, E);
    relu_kernel<<<gElem, 256, 0, stream>>>(x2, n128);
    // layer 2
    gemm128_kernel<<<gGemm, 256, 0, stream>>>(x2, W2, h, N, 128);
    preset_kernel<<<gElem, 256, 0, stream>>>(h, dinv, b2, x3, n128);
    aggregate_kernel<<<4096, 256, 0, stream>>>(h, row, col, dinv, x3, E);
    relu_kernel<<<gElem, 256, 0, stream>>>(x3, n128);
    // head
    out_gemm_kernel<<<(N + 3) / 4, 256, 0, stream>>>(x1, x2, x3, Wout, bout, out, N);
}

// Round 2
// 824.065 us; speedup vs baseline: 3.0847x; 3.0847x over previous
//
#include <hip/hip_runtime.h>

#define HID 128
#define NOUT 40
#define SCAN_B 256

// ---------------- edge dtype detect + convert ----------------
__global__ void detect_fmt_kernel(const unsigned int* __restrict__ e, int* __restrict__ flag) {
    int t = threadIdx.x;  // 64 threads, one wave
    unsigned int v = e[2 * t + 1];
    unsigned long long ball = __ballot(v == 0u);
    if (t == 0) *flag = (ball == ~0ull) ? 1 : 0;
}

__global__ void convert_kernel(const void* __restrict__ eix, const int* __restrict__ flag,
                               int* __restrict__ rc, int n2e) {
    int i = blockIdx.x * blockDim.x + threadIdx.x;
    if (i >= n2e) return;
    int f = *flag;
    int v;
    if (f) v = (int)(((const long long*)eix)[i]);
    else   v = ((const int*)eix)[i];
    rc[i] = v;
}

__global__ void degree_kernel(const int* __restrict__ col, int* __restrict__ deg, int E) {
    int i = blockIdx.x * blockDim.x + threadIdx.x;
    if (i < E) atomicAdd(&deg[col[i]], 1);
}

__global__ void dinv_kernel(const int* __restrict__ deg, float* __restrict__ dinv, int n) {
    int i = blockIdx.x * blockDim.x + threadIdx.x;
    if (i < n) dinv[i] = rsqrtf((float)deg[i] + 1.0f);  // +1 = self loop
}

// ---------------- exclusive scan (3 kernels) ----------------
__global__ void scan1_kernel(const int* __restrict__ deg, int* __restrict__ offs,
                             int* __restrict__ bsum, int N) {
    __shared__ int s[SCAN_B];
    int i = blockIdx.x * SCAN_B + threadIdx.x;
    int v = (i < N) ? deg[i] : 0;
    s[threadIdx.x] = v;
    __syncthreads();
    for (int d = 1; d < SCAN_B; d <<= 1) {
        int t = (threadIdx.x >= d) ? s[threadIdx.x - d] : 0;
        __syncthreads();
        s[threadIdx.x] += t;
        __syncthreads();
    }
    if (i < N) offs[i] = s[threadIdx.x] - v;  // exclusive
    if (threadIdx.x == SCAN_B - 1) bsum[blockIdx.x] = s[SCAN_B - 1];
}

__global__ void scan2_kernel(int* __restrict__ bsum, int nb) {
    __shared__ int s[SCAN_B];
    int v = (threadIdx.x < nb) ? bsum[threadIdx.x] : 0;
    s[threadIdx.x] = v;
    __syncthreads();
    for (int d = 1; d < SCAN_B; d <<= 1) {
        int t = (threadIdx.x >= d) ? s[threadIdx.x - d] : 0;
        __syncthreads();
        s[threadIdx.x] += t;
        __syncthreads();
    }
    if (threadIdx.x < nb) bsum[threadIdx.x] = s[threadIdx.x] - v;  // exclusive
}

__global__ void scan3_kernel(int* __restrict__ offs, const int* __restrict__ bsum, int N, int E) {
    int i = blockIdx.x * SCAN_B + threadIdx.x;
    if (i < N) offs[i] += bsum[blockIdx.x];
    if (blockIdx.x == 0 && threadIdx.x == 0) offs[N] = E;
}

// cursor[c] = next free CSR slot for destination c (cursor pre-copied from offs)
__global__ void fill_csr_kernel(const int* __restrict__ row, const int* __restrict__ col,
                                int* __restrict__ cursor, int* __restrict__ csrc, int E) {
    int e = blockIdx.x * blockDim.x + threadIdx.x;
    if (e >= E) return;
    int r = row[e];
    int c = col[e];
    int p = atomicAdd(&cursor[c], 1);
    csrc[p] = r;
}

// ---------------- fp32 GEMM: C[M,128] = A[M,K] @ B[K,128] ----------------
__global__ __launch_bounds__(256) void gemm128_kernel(
    const float* __restrict__ A, const float* __restrict__ B,
    float* __restrict__ C, int M, int K) {
    __shared__ float As[32][68];   // [k][m], padded
    __shared__ float Bs[32][132];  // [k][h], padded
    const int tid = threadIdx.x;
    const int tx = tid & 15;
    const int ty = tid >> 4;
    const int bm = blockIdx.x * 64;

    float acc[4][8];
#pragma unroll
    for (int i = 0; i < 4; ++i)
#pragma unroll
        for (int j = 0; j < 8; ++j) acc[i][j] = 0.f;

    const int kk = tid & 31;
    const int am = tid >> 5;
    const int bh = tid & 127;
    const int bk = tid >> 7;

    for (int k0 = 0; k0 < K; k0 += 32) {
#pragma unroll
        for (int p = 0; p < 8; ++p) {
            int m = am + p * 8;
            int gr = bm + m;
            As[kk][m] = (gr < M) ? A[(size_t)gr * K + (k0 + kk)] : 0.f;
        }
#pragma unroll
        for (int p = 0; p < 16; ++p) {
            int r = bk + p * 2;
            Bs[r][bh] = B[(size_t)(k0 + r) * HID + bh];
        }
        __syncthreads();
#pragma unroll
        for (int k = 0; k < 32; ++k) {
            float a0 = As[k][ty * 4 + 0];
            float a1 = As[k][ty * 4 + 1];
            float a2 = As[k][ty * 4 + 2];
            float a3 = As[k][ty * 4 + 3];
            float b0 = Bs[k][tx * 8 + 0];
            float b1 = Bs[k][tx * 8 + 1];
            float b2 = Bs[k][tx * 8 + 2];
            float b3 = Bs[k][tx * 8 + 3];
            float b4 = Bs[k][tx * 8 + 4];
            float b5 = Bs[k][tx * 8 + 5];
            float b6 = Bs[k][tx * 8 + 6];
            float b7 = Bs[k][tx * 8 + 7];
            acc[0][0] += a0 * b0; acc[0][1] += a0 * b1; acc[0][2] += a0 * b2; acc[0][3] += a0 * b3;
            acc[0][4] += a0 * b4; acc[0][5] += a0 * b5; acc[0][6] += a0 * b6; acc[0][7] += a0 * b7;
            acc[1][0] += a1 * b0; acc[1][1] += a1 * b1; acc[1][2] += a1 * b2; acc[1][3] += a1 * b3;
            acc[1][4] += a1 * b4; acc[1][5] += a1 * b5; acc[1][6] += a1 * b6; acc[1][7] += a1 * b7;
            acc[2][0] += a2 * b0; acc[2][1] += a2 * b1; acc[2][2] += a2 * b2; acc[2][3] += a2 * b3;
            acc[2][4] += a2 * b4; acc[2][5] += a2 * b5; acc[2][6] += a2 * b6; acc[2][7] += a2 * b7;
            acc[3][0] += a3 * b0; acc[3][1] += a3 * b1; acc[3][2] += a3 * b2; acc[3][3] += a3 * b3;
            acc[3][4] += a3 * b4; acc[3][5] += a3 * b5; acc[3][6] += a3 * b6; acc[3][7] += a3 * b7;
        }
        __syncthreads();
    }

#pragma unroll
    for (int i = 0; i < 4; ++i) {
        int gr = bm + ty * 4 + i;
        if (gr < M) {
            float4* cp = (float4*)(C + (size_t)gr * HID + tx * 8);
            cp[0] = make_float4(acc[i][0], acc[i][1], acc[i][2], acc[i][3]);
            cp[1] = make_float4(acc[i][4], acc[i][5], acc[i][6], acc[i][7]);
        }
    }
}

// ---------------- CSR gather-aggregate, fused self-loop + bias + ReLU ----------------
// one wave per node; lane owns float2 (2 of 128 feature dims)
__global__ __launch_bounds__(256) void agg_csr_kernel(
    const float* __restrict__ h, const int* __restrict__ offs, const int* __restrict__ csrc,
    const float* __restrict__ dinv, const float* __restrict__ bias,
    float* __restrict__ xo, int N) {
    const int lane = threadIdx.x & 63;
    const int n = (blockIdx.x * blockDim.x + threadIdx.x) >> 6;
    if (n >= N) return;
    const float2* h2 = (const float2*)h;
    const float d = dinv[n];
    float2 self = h2[(size_t)n * 64 + lane];
    float2 acc;
    acc.x = self.x * d * d + bias[lane * 2 + 0];
    acc.y = self.y * d * d + bias[lane * 2 + 1];
    const int s = offs[n];
    const int e1 = offs[n + 1];
    for (int e = s; e < e1; ++e) {
        int r = csrc[e];
        float w = dinv[r] * d;
        float2 v = h2[(size_t)r * 64 + lane];
        acc.x += v.x * w;
        acc.y += v.y * w;
    }
    acc.x = fmaxf(acc.x, 0.f);
    acc.y = fmaxf(acc.y, 0.f);
    ((float2*)xo)[(size_t)n * 64 + lane] = acc;
}

// ---------------- head ----------------
__global__ __launch_bounds__(256) void out_gemm_kernel(
    const float* __restrict__ x1, const float* __restrict__ x2, const float* __restrict__ x3,
    const float* __restrict__ Wout, const float* __restrict__ bout,
    float* __restrict__ out, int M) {
    __shared__ float Ws[384 * NOUT];  // 61.4 KB
    const int tid = threadIdx.x;
    for (int i = tid; i < 384 * NOUT; i += 256) Ws[i] = Wout[i];
    __syncthreads();

    const int o = tid & 63;
    const int oe = (o < NOUT) ? o : (NOUT - 1);
    const int n = blockIdx.x * 4 + (tid >> 6);
    if (n >= M) return;

    float acc = bout[oe];
    const float* xs[3] = {x1, x2, x3};
#pragma unroll
    for (int s = 0; s < 3; ++s) {
        const float4* xp = (const float4*)(xs[s] + (size_t)n * HID);
        const float* Wp = Ws + s * HID * NOUT;
#pragma unroll 4
        for (int k4 = 0; k4 < 32; ++k4) {
            float4 v = xp[k4];
            acc += v.x * Wp[(k4 * 4 + 0) * NOUT + oe];
            acc += v.y * Wp[(k4 * 4 + 1) * NOUT + oe];
            acc += v.z * Wp[(k4 * 4 + 2) * NOUT + oe];
            acc += v.w * Wp[(k4 * 4 + 3) * NOUT + oe];
        }
    }
    if (o < NOUT) out[(size_t)n * NOUT + o] = acc;
}

// ---------------- launch ----------------
static inline size_t align_up(size_t x, size_t a) { return (x + a - 1) / a * a; }

extern "C" void kernel_launch(void* const* d_in, const int* in_sizes, int n_in,
                              void* d_out, int out_size, void* d_ws, size_t ws_size,
                              hipStream_t stream) {
    const float* x    = (const float*)d_in[0];
    const void*  eix  = d_in[1];
    const float* W0   = (const float*)d_in[2];
    const float* b0   = (const float*)d_in[3];
    const float* W1   = (const float*)d_in[4];
    const float* b1   = (const float*)d_in[5];
    const float* W2   = (const float*)d_in[6];
    const float* b2   = (const float*)d_in[7];
    const float* Wout = (const float*)d_in[8];
    const float* bout = (const float*)d_in[9];
    float* out = (float*)d_out;

    const int D = 256;
    const int N = in_sizes[0] / D;        // 50000
    const int E = in_sizes[1] / 2;        // 800000

    // workspace carve-out
    char* w = (char*)d_ws;
    size_t off = 0;
    int* rc = (int*)(w + off);            off = align_up(off + (size_t)2 * E * 4, 256);
    int* deg = (int*)(w + off);           off = align_up(off + (size_t)N * 4, 256);
    float* dinv = (float*)(w + off);      off = align_up(off + (size_t)N * 4, 256);
    int* offs = (int*)(w + off);          off = align_up(off + (size_t)(N + 1) * 4, 256);
    int* cursor = (int*)(w + off);        off = align_up(off + (size_t)N * 4, 256);
    int* bsum = (int*)(w + off);          off = align_up(off + 1024 * 4, 256);
    int* flag = (int*)(w + off);          off = align_up(off + 16, 256);
    int* csrc = (int*)(w + off);          off = align_up(off + (size_t)E * 4, 256);
    float* h  = (float*)(w + off);        off = align_up(off + (size_t)N * HID * 4, 256);
    float* x1 = (float*)(w + off);        off = align_up(off + (size_t)N * HID * 4, 256);
    float* x2 = (float*)(w + off);        off = align_up(off + (size_t)N * HID * 4, 256);
    float* x3 = (float*)(w + off);        off = align_up(off + (size_t)N * HID * 4, 256);
    (void)ws_size;

    int* row = rc;
    int* col = rc + E;

    // ---- graph prep ----
    detect_fmt_kernel<<<1, 64, 0, stream>>>((const unsigned int*)eix, flag);
    convert_kernel<<<(2 * E + 255) / 256, 256, 0, stream>>>(eix, flag, rc, 2 * E);
    hipMemsetAsync(deg, 0, (size_t)N * 4, stream);
    degree_kernel<<<(E + 255) / 256, 256, 0, stream>>>(col, deg, E);
    dinv_kernel<<<(N + 255) / 256, 256, 0, stream>>>(deg, dinv, N);

    const int nb = (N + SCAN_B - 1) / SCAN_B;  // 196 <= 256
    scan1_kernel<<<nb, SCAN_B, 0, stream>>>(deg, offs, bsum, N);
    scan2_kernel<<<1, SCAN_B, 0, stream>>>(bsum, nb);
    scan3_kernel<<<nb, SCAN_B, 0, stream>>>(offs, bsum, N, E);
    hipMemcpyAsync(cursor, offs, (size_t)N * 4, hipMemcpyDeviceToDevice, stream);
    fill_csr_kernel<<<(E + 255) / 256, 256, 0, stream>>>(row, col, cursor, csrc, E);

    const int gGemm = (N + 63) / 64;
    const int gAgg = (N * 64 + 255) / 256;   // one wave per node

    // layer 0
    gemm128_kernel<<<gGemm, 256, 0, stream>>>(x, W0, h, N, 256);
    agg_csr_kernel<<<gAgg, 256, 0, stream>>>(h, offs, csrc, dinv, b0, x1, N);
    // layer 1
    gemm128_kernel<<<gGemm, 256, 0, stream>>>(x1, W1, h, N, 128);
    agg_csr_kernel<<<gAgg, 256, 0, stream>>>(h, offs, csrc, dinv, b1, x2, N);
    // layer 2
    gemm128_kernel<<<gGemm, 256, 0, stream>>>(x2, W2, h, N, 128);
    agg_csr_kernel<<<gAgg, 256, 0, stream>>>(h, offs, csrc, dinv, b2, x3, N);
    // head
    out_gemm_kernel<<<(N + 3) / 4, 256, 0, stream>>>(x1, x2, x3, Wout, bout, out, N);
}

// Round 3
// 537.574 us; speedup vs baseline: 4.7286x; 1.5329x over previous
//
#include <hip/hip_runtime.h>

#define HID 128
#define NOUT 40
#define SCAN_B 256

typedef __attribute__((ext_vector_type(8))) short bf16x8;
typedef __attribute__((ext_vector_type(4))) float f32x4;

__device__ inline float bf2f(unsigned short u) {
    unsigned int t = ((unsigned int)u) << 16;
    float f;
    __builtin_memcpy(&f, &t, 4);
    return f;
}
__device__ inline unsigned short f2bf(float f) {
    unsigned int x;
    __builtin_memcpy(&x, &f, 4);
    unsigned int r = (x + 0x7fffu + ((x >> 16) & 1u)) >> 16;  // RNE
    return (unsigned short)r;
}

// ---------------- edge dtype detect + convert ----------------
__global__ void detect_fmt_kernel(const unsigned int* __restrict__ e, int* __restrict__ flag) {
    int t = threadIdx.x;  // one wave
    unsigned int v = e[2 * t + 1];
    unsigned long long ball = __ballot(v == 0u);
    if (t == 0) *flag = (ball == ~0ull) ? 1 : 0;
}

__global__ void convert_kernel(const void* __restrict__ eix, const int* __restrict__ flag,
                               int* __restrict__ rc, int n2e) {
    int i = blockIdx.x * blockDim.x + threadIdx.x;
    if (i >= n2e) return;
    int f = *flag;
    int v;
    if (f) v = (int)(((const long long*)eix)[i]);
    else   v = ((const int*)eix)[i];
    rc[i] = v;
}

__global__ void degree_kernel(const int* __restrict__ col, int* __restrict__ deg, int E) {
    int i = blockIdx.x * blockDim.x + threadIdx.x;
    if (i < E) atomicAdd(&deg[col[i]], 1);
}

__global__ void dinv_kernel(const int* __restrict__ deg, float* __restrict__ dinv, int n) {
    int i = blockIdx.x * blockDim.x + threadIdx.x;
    if (i < n) dinv[i] = rsqrtf((float)deg[i] + 1.0f);  // +1 self loop
}

// ---------------- exclusive scan ----------------
__global__ void scan1_kernel(const int* __restrict__ deg, int* __restrict__ offs,
                             int* __restrict__ bsum, int N) {
    __shared__ int s[SCAN_B];
    int i = blockIdx.x * SCAN_B + threadIdx.x;
    int v = (i < N) ? deg[i] : 0;
    s[threadIdx.x] = v;
    __syncthreads();
    for (int d = 1; d < SCAN_B; d <<= 1) {
        int t = (threadIdx.x >= d) ? s[threadIdx.x - d] : 0;
        __syncthreads();
        s[threadIdx.x] += t;
        __syncthreads();
    }
    if (i < N) offs[i] = s[threadIdx.x] - v;
    if (threadIdx.x == SCAN_B - 1) bsum[blockIdx.x] = s[SCAN_B - 1];
}

__global__ void scan2_kernel(int* __restrict__ bsum, int nb) {
    __shared__ int s[SCAN_B];
    int v = (threadIdx.x < nb) ? bsum[threadIdx.x] : 0;
    s[threadIdx.x] = v;
    __syncthreads();
    for (int d = 1; d < SCAN_B; d <<= 1) {
        int t = (threadIdx.x >= d) ? s[threadIdx.x - d] : 0;
        __syncthreads();
        s[threadIdx.x] += t;
        __syncthreads();
    }
    if (threadIdx.x < nb) bsum[threadIdx.x] = s[threadIdx.x] - v;
}

__global__ void scan3_kernel(int* __restrict__ offs, const int* __restrict__ bsum, int N, int E) {
    int i = blockIdx.x * SCAN_B + threadIdx.x;
    if (i < N) offs[i] += bsum[blockIdx.x];
    if (blockIdx.x == 0 && threadIdx.x == 0) offs[N] = E;
}

__global__ void fill_csr_kernel(const int* __restrict__ row, const int* __restrict__ col,
                                int* __restrict__ cursor, int* __restrict__ csrc, int E) {
    int e = blockIdx.x * blockDim.x + threadIdx.x;
    if (e >= E) return;
    int r = row[e];
    int c = col[e];
    int p = atomicAdd(&cursor[c], 1);
    csrc[p] = r;
}

// ---------------- conversions ----------------
// 8 floats -> 8 bf16 per thread
__global__ void cvt_bf16_kernel(const float* __restrict__ src, unsigned short* __restrict__ dst, int n8) {
    int i = blockIdx.x * blockDim.x + threadIdx.x;
    if (i >= n8) return;
    const float4* s4 = (const float4*)src;
    float4 a = s4[2 * i], b = s4[2 * i + 1];
    uint4 o;
    o.x = (unsigned int)f2bf(a.x) | ((unsigned int)f2bf(a.y) << 16);
    o.y = (unsigned int)f2bf(a.z) | ((unsigned int)f2bf(a.w) << 16);
    o.z = (unsigned int)f2bf(b.x) | ((unsigned int)f2bf(b.y) << 16);
    o.w = (unsigned int)f2bf(b.z) | ((unsigned int)f2bf(b.w) << 16);
    ((uint4*)dst)[i] = o;
}

// src f32 [K][Nc] -> dst bf16 [Nr][K] (transpose + pad rows Nc..Nr-1 with 0)
__global__ void wt_kernel(const float* __restrict__ src, unsigned short* __restrict__ dst,
                          int K, int Nc, int Nr) {
    int idx = blockIdx.x * blockDim.x + threadIdx.x;
    if (idx >= Nr * K) return;
    int n = idx / K, k = idx - n * K;
    float v = (n < Nc) ? src[(size_t)k * Nc + n] : 0.f;
    dst[idx] = f2bf(v);
}

// ---------------- MFMA GEMM: H[M][128] = A[M][K] @ W   (Wt bf16 [128][K]) ----------------
// LDS-free: BM=64, 4 waves (2x2), per-wave 32x64, fragments straight from global.
__global__ __launch_bounds__(256) void gemm_mfma_kernel(
    const unsigned short* __restrict__ A, const unsigned short* __restrict__ Wt,
    unsigned short* __restrict__ H, int M, int K) {
    const int tid = threadIdx.x;
    const int lane = tid & 63;
    const int w = tid >> 6;
    const int wr = w >> 1, wc = w & 1;
    const int lr = lane & 15;
    const int ko = lane >> 4;
    const int bm = blockIdx.x * 64;

    f32x4 acc[2][4];
#pragma unroll
    for (int i = 0; i < 2; ++i)
#pragma unroll
        for (int j = 0; j < 4; ++j) acc[i][j] = (f32x4){0.f, 0.f, 0.f, 0.f};

    size_t aoff[2];
#pragma unroll
    for (int mi = 0; mi < 2; ++mi) {
        int R = bm + wr * 32 + mi * 16 + lr;
        if (R >= M) R = M - 1;
        aoff[mi] = (size_t)R * K + ko * 8;
    }
    size_t boff[4];
#pragma unroll
    for (int ni = 0; ni < 4; ++ni) {
        int n = wc * 64 + ni * 16 + lr;
        boff[ni] = (size_t)n * K + ko * 8;
    }

#pragma unroll 4
    for (int k0 = 0; k0 < K; k0 += 32) {
        bf16x8 a[2], b[4];
#pragma unroll
        for (int mi = 0; mi < 2; ++mi) a[mi] = *(const bf16x8*)(A + aoff[mi] + k0);
#pragma unroll
        for (int ni = 0; ni < 4; ++ni) b[ni] = *(const bf16x8*)(Wt + boff[ni] + k0);
#pragma unroll
        for (int mi = 0; mi < 2; ++mi)
#pragma unroll
            for (int ni = 0; ni < 4; ++ni)
                acc[mi][ni] = __builtin_amdgcn_mfma_f32_16x16x32_bf16(a[mi], b[ni], acc[mi][ni], 0, 0, 0);
    }

    // C/D layout: col = lane&15, row = (lane>>4)*4 + reg
#pragma unroll
    for (int mi = 0; mi < 2; ++mi) {
        int Rb = bm + wr * 32 + mi * 16 + ko * 4;
#pragma unroll
        for (int r = 0; r < 4; ++r) {
            int R = Rb + r;
            if (R < M) {
#pragma unroll
                for (int ni = 0; ni < 4; ++ni) {
                    int C = wc * 64 + ni * 16 + lr;
                    H[(size_t)R * HID + C] = f2bf(acc[mi][ni][r]);
                }
            }
        }
    }
}

// ---------------- CSR gather-aggregate (bf16 in/out, fp32 accum) ----------------
__global__ __launch_bounds__(256) void agg_csr_kernel(
    const unsigned int* __restrict__ h32, const int* __restrict__ offs, const int* __restrict__ csrc,
    const float* __restrict__ dinv, const float* __restrict__ bias,
    unsigned int* __restrict__ xo, int N) {
    const int lane = threadIdx.x & 63;
    const int n = (blockIdx.x * blockDim.x + threadIdx.x) >> 6;
    if (n >= N) return;
    const float d = dinv[n];
    unsigned int sv = h32[(size_t)n * 64 + lane];
    float ax = bf2f((unsigned short)(sv & 0xffff)) * d * d + bias[2 * lane + 0];
    float ay = bf2f((unsigned short)(sv >> 16))    * d * d + bias[2 * lane + 1];
    const int s = offs[n];
    const int e1 = offs[n + 1];
    for (int e = s; e < e1; ++e) {
        int r = csrc[e];
        float wg = dinv[r] * d;
        unsigned int v = h32[(size_t)r * 64 + lane];
        ax += bf2f((unsigned short)(v & 0xffff)) * wg;
        ay += bf2f((unsigned short)(v >> 16))    * wg;
    }
    ax = fmaxf(ax, 0.f);
    ay = fmaxf(ay, 0.f);
    xo[(size_t)n * 64 + lane] = (unsigned int)f2bf(ax) | ((unsigned int)f2bf(ay) << 16);
}

// ---------------- head: out[M][40] = [x1|x2|x3] @ Wout + bout  (Woutt bf16 [48][384]) ----------------
__global__ __launch_bounds__(256) void head_mfma_kernel(
    const unsigned short* __restrict__ x1, const unsigned short* __restrict__ x2,
    const unsigned short* __restrict__ x3, const unsigned short* __restrict__ Wt,
    const float* __restrict__ bout, float* __restrict__ out, int M) {
    const int tid = threadIdx.x;
    const int lane = tid & 63;
    const int w = tid >> 6;
    const int lr = lane & 15;
    const int ko = lane >> 4;
    const int bm = blockIdx.x * 64;
    int R = bm + w * 16 + lr;
    if (R >= M) R = M - 1;
    const unsigned short* xs[3] = {x1, x2, x3};

    f32x4 acc[3];
#pragma unroll
    for (int i = 0; i < 3; ++i) acc[i] = (f32x4){0.f, 0.f, 0.f, 0.f};

#pragma unroll
    for (int s = 0; s < 3; ++s) {
        const unsigned short* xp = xs[s] + (size_t)R * HID + ko * 8;
#pragma unroll
        for (int c = 0; c < 4; ++c) {
            bf16x8 a = *(const bf16x8*)(xp + c * 32);
#pragma unroll
            for (int ni = 0; ni < 3; ++ni) {
                bf16x8 b = *(const bf16x8*)(Wt + (size_t)(ni * 16 + lr) * 384 + s * 128 + c * 32 + ko * 8);
                acc[ni] = __builtin_amdgcn_mfma_f32_16x16x32_bf16(a, b, acc[ni], 0, 0, 0);
            }
        }
    }

    int Rb = bm + w * 16 + ko * 4;
#pragma unroll
    for (int r = 0; r < 4; ++r) {
        int Ro = Rb + r;
        if (Ro < M) {
#pragma unroll
            for (int ni = 0; ni < 3; ++ni) {
                int C = ni * 16 + lr;
                if (C < NOUT) out[(size_t)Ro * NOUT + C] = acc[ni][r] + bout[C];
            }
        }
    }
}

// ---------------- launch ----------------
static inline size_t align_up(size_t x, size_t a) { return (x + a - 1) / a * a; }

extern "C" void kernel_launch(void* const* d_in, const int* in_sizes, int n_in,
                              void* d_out, int out_size, void* d_ws, size_t ws_size,
                              hipStream_t stream) {
    const float* x    = (const float*)d_in[0];
    const void*  eix  = d_in[1];
    const float* W0   = (const float*)d_in[2];
    const float* b0   = (const float*)d_in[3];
    const float* W1   = (const float*)d_in[4];
    const float* b1   = (const float*)d_in[5];
    const float* W2   = (const float*)d_in[6];
    const float* b2   = (const float*)d_in[7];
    const float* Wout = (const float*)d_in[8];
    const float* bout = (const float*)d_in[9];
    float* out = (float*)d_out;

    const int D = 256;
    const int N = in_sizes[0] / D;        // 50000
    const int E = in_sizes[1] / 2;        // 800000

    // workspace carve-out
    char* w = (char*)d_ws;
    size_t off = 0;
    int* rc = (int*)(w + off);              off = align_up(off + (size_t)2 * E * 4, 256);
    int* deg = (int*)(w + off);             off = align_up(off + (size_t)N * 4, 256);
    float* dinv = (float*)(w + off);        off = align_up(off + (size_t)N * 4, 256);
    int* offs = (int*)(w + off);            off = align_up(off + (size_t)(N + 1) * 4, 256);
    int* cursor = (int*)(w + off);          off = align_up(off + (size_t)N * 4, 256);
    int* bsum = (int*)(w + off);            off = align_up(off + 1024 * 4, 256);
    int* flag = (int*)(w + off);            off = align_up(off + 16, 256);
    int* csrc = (int*)(w + off);            off = align_up(off + (size_t)E * 4, 256);
    unsigned short* xb  = (unsigned short*)(w + off); off = align_up(off + (size_t)N * D * 2, 256);
    unsigned short* h   = (unsigned short*)(w + off); off = align_up(off + (size_t)N * HID * 2, 256);
    unsigned short* x1b = (unsigned short*)(w + off); off = align_up(off + (size_t)N * HID * 2, 256);
    unsigned short* x2b = (unsigned short*)(w + off); off = align_up(off + (size_t)N * HID * 2, 256);
    unsigned short* x3b = (unsigned short*)(w + off); off = align_up(off + (size_t)N * HID * 2, 256);
    unsigned short* W0t = (unsigned short*)(w + off); off = align_up(off + (size_t)HID * 256 * 2, 256);
    unsigned short* W1t = (unsigned short*)(w + off); off = align_up(off + (size_t)HID * HID * 2, 256);
    unsigned short* W2t = (unsigned short*)(w + off); off = align_up(off + (size_t)HID * HID * 2, 256);
    unsigned short* Wot = (unsigned short*)(w + off); off = align_up(off + (size_t)48 * 384 * 2, 256);
    (void)ws_size;

    int* row = rc;
    int* col = rc + E;

    // ---- graph prep ----
    detect_fmt_kernel<<<1, 64, 0, stream>>>((const unsigned int*)eix, flag);
    convert_kernel<<<(2 * E + 255) / 256, 256, 0, stream>>>(eix, flag, rc, 2 * E);
    hipMemsetAsync(deg, 0, (size_t)N * 4, stream);
    degree_kernel<<<(E + 255) / 256, 256, 0, stream>>>(col, deg, E);
    dinv_kernel<<<(N + 255) / 256, 256, 0, stream>>>(deg, dinv, N);

    const int nb = (N + SCAN_B - 1) / SCAN_B;  // 196 <= 256
    scan1_kernel<<<nb, SCAN_B, 0, stream>>>(deg, offs, bsum, N);
    scan2_kernel<<<1, SCAN_B, 0, stream>>>(bsum, nb);
    scan3_kernel<<<nb, SCAN_B, 0, stream>>>(offs, bsum, N, E);
    hipMemcpyAsync(cursor, offs, (size_t)N * 4, hipMemcpyDeviceToDevice, stream);
    fill_csr_kernel<<<(E + 255) / 256, 256, 0, stream>>>(row, col, cursor, csrc, E);

    // ---- weights / input to bf16 ----
    cvt_bf16_kernel<<<(N * D / 8 + 255) / 256, 256, 0, stream>>>(x, xb, N * D / 8);
    wt_kernel<<<(HID * 256 + 255) / 256, 256, 0, stream>>>(W0, W0t, 256, HID, HID);
    wt_kernel<<<(HID * HID + 255) / 256, 256, 0, stream>>>(W1, W1t, HID, HID, HID);
    wt_kernel<<<(HID * HID + 255) / 256, 256, 0, stream>>>(W2, W2t, HID, HID, HID);
    wt_kernel<<<(48 * 384 + 255) / 256, 256, 0, stream>>>(Wout, Wot, 384, NOUT, 48);

    const int gGemm = (N + 63) / 64;
    const int gAgg = (N * 64 + 255) / 256;

    // layer 0
    gemm_mfma_kernel<<<gGemm, 256, 0, stream>>>(xb, W0t, h, N, 256);
    agg_csr_kernel<<<gAgg, 256, 0, stream>>>((const unsigned int*)h, offs, csrc, dinv, b0, (unsigned int*)x1b, N);
    // layer 1
    gemm_mfma_kernel<<<gGemm, 256, 0, stream>>>(x1b, W1t, h, N, HID);
    agg_csr_kernel<<<gAgg, 256, 0, stream>>>((const unsigned int*)h, offs, csrc, dinv, b1, (unsigned int*)x2b, N);
    // layer 2
    gemm_mfma_kernel<<<gGemm, 256, 0, stream>>>(x2b, W2t, h, N, HID);
    agg_csr_kernel<<<gAgg, 256, 0, stream>>>((const unsigned int*)h, offs, csrc, dinv, b2, (unsigned int*)x3b, N);
    // head
    head_mfma_kernel<<<gGemm, 256, 0, stream>>>(x1b, x2b, x3b, Wot, bout, out, N);
}

// Round 4
// 400.881 us; speedup vs baseline: 6.3409x; 1.3410x over previous
//
#include <hip/hip_runtime.h>

#define HID 128
#define NOUT 40
#define SCAN_B 256

typedef __attribute__((ext_vector_type(8))) short bf16x8;
typedef __attribute__((ext_vector_type(4))) float f32x4;

__device__ inline float bf2f(unsigned short u) {
    unsigned int t = ((unsigned int)u) << 16;
    float f;
    __builtin_memcpy(&f, &t, 4);
    return f;
}
__device__ inline unsigned short f2bf(float f) {
    unsigned int x;
    __builtin_memcpy(&x, &f, 4);
    unsigned int r = (x + 0x7fffu + ((x >> 16) & 1u)) >> 16;  // RNE
    return (unsigned short)r;
}
__device__ inline bf16x8 pack_bf8(float4 u, float4 v) {
    bf16x8 r;
    r[0] = (short)f2bf(u.x); r[1] = (short)f2bf(u.y);
    r[2] = (short)f2bf(u.z); r[3] = (short)f2bf(u.w);
    r[4] = (short)f2bf(v.x); r[5] = (short)f2bf(v.y);
    r[6] = (short)f2bf(v.z); r[7] = (short)f2bf(v.w);
    return r;
}

// ---------------- edge dtype detect ----------------
__global__ void detect_fmt_kernel(const unsigned int* __restrict__ e, int* __restrict__ flag) {
    int t = threadIdx.x;  // one wave
    unsigned int v = e[2 * t + 1];
    unsigned long long ball = __ballot(v == 0u);
    if (t == 0) *flag = (ball == ~0ull) ? 1 : 0;
}

// convert to int32 AND count in-degrees (col half) in one pass
__global__ void convert_kernel(const void* __restrict__ eix, const int* __restrict__ flag,
                               int* __restrict__ rc, int* __restrict__ deg, int n2e) {
    int i = blockIdx.x * blockDim.x + threadIdx.x;
    if (i >= n2e) return;
    int f = *flag;
    int v;
    if (f) v = (int)(((const long long*)eix)[i]);
    else   v = ((const int*)eix)[i];
    rc[i] = v;
    if (i >= (n2e >> 1)) atomicAdd(&deg[v], 1);  // col entries
}

// ---------------- exclusive scan (+ fused dinv in pass 1, cursor in pass 3) ----------------
__global__ void scan1_kernel(const int* __restrict__ deg, int* __restrict__ offs,
                             int* __restrict__ bsum, float* __restrict__ dinv, int N) {
    __shared__ int s[SCAN_B];
    int i = blockIdx.x * SCAN_B + threadIdx.x;
    int v = (i < N) ? deg[i] : 0;
    if (i < N) dinv[i] = rsqrtf((float)v + 1.0f);  // +1 self loop
    s[threadIdx.x] = v;
    __syncthreads();
    for (int d = 1; d < SCAN_B; d <<= 1) {
        int t = (threadIdx.x >= d) ? s[threadIdx.x - d] : 0;
        __syncthreads();
        s[threadIdx.x] += t;
        __syncthreads();
    }
    if (i < N) offs[i] = s[threadIdx.x] - v;
    if (threadIdx.x == SCAN_B - 1) bsum[blockIdx.x] = s[SCAN_B - 1];
}

__global__ void scan2_kernel(int* __restrict__ bsum, int nb) {
    __shared__ int s[SCAN_B];
    int v = (threadIdx.x < nb) ? bsum[threadIdx.x] : 0;
    s[threadIdx.x] = v;
    __syncthreads();
    for (int d = 1; d < SCAN_B; d <<= 1) {
        int t = (threadIdx.x >= d) ? s[threadIdx.x - d] : 0;
        __syncthreads();
        s[threadIdx.x] += t;
        __syncthreads();
    }
    if (threadIdx.x < nb) bsum[threadIdx.x] = s[threadIdx.x] - v;
}

__global__ void scan3_kernel(int* __restrict__ offs, const int* __restrict__ bsum,
                             int* __restrict__ cursor, int N, int E) {
    int i = blockIdx.x * SCAN_B + threadIdx.x;
    if (i < N) {
        int v = offs[i] + bsum[blockIdx.x];
        offs[i] = v;
        cursor[i] = v;
    }
    if (blockIdx.x == 0 && threadIdx.x == 0) offs[N] = E;
}

// CSR fill: also precompute per-edge weight dinv[r]*dinv[c]
__global__ void fill_csr_kernel(const int* __restrict__ row, const int* __restrict__ col,
                                const float* __restrict__ dinv, int* __restrict__ cursor,
                                int* __restrict__ csrc, float* __restrict__ wgt, int E) {
    int e = blockIdx.x * blockDim.x + threadIdx.x;
    if (e >= E) return;
    int r = row[e];
    int c = col[e];
    int p = atomicAdd(&cursor[c], 1);
    csrc[p] = r;
    wgt[p] = dinv[r] * dinv[c];
}

// src f32 [K][Nc] -> dst bf16 [Nr][K] (transpose + zero-pad rows Nc..Nr-1)
__global__ void wt_kernel(const float* __restrict__ src, unsigned short* __restrict__ dst,
                          int K, int Nc, int Nr) {
    int idx = blockIdx.x * blockDim.x + threadIdx.x;
    if (idx >= Nr * K) return;
    int n = idx / K, k = idx - n * K;
    float v = (n < Nc) ? src[(size_t)k * Nc + n] : 0.f;
    dst[idx] = f2bf(v);
}

// ---------------- MFMA GEMM: H[M][128] = A[M][K] @ W   (Wt bf16 [128][K]) ----------------
// LDS-free: BM=64, 4 waves (2x2), per-wave 32x64, fragments straight from global.
// AF32: A is f32 (layer 0 input), converted to bf16 fragments inline.
template <bool AF32>
__global__ __launch_bounds__(256) void gemm_mfma_kernel(
    const void* __restrict__ Ap, const unsigned short* __restrict__ Wt,
    unsigned short* __restrict__ H, int M, int K) {
    const int tid = threadIdx.x;
    const int lane = tid & 63;
    const int w = tid >> 6;
    const int wr = w >> 1, wc = w & 1;
    const int lr = lane & 15;
    const int ko = lane >> 4;
    const int bm = blockIdx.x * 64;

    f32x4 acc[2][4];
#pragma unroll
    for (int i = 0; i < 2; ++i)
#pragma unroll
        for (int j = 0; j < 4; ++j) acc[i][j] = (f32x4){0.f, 0.f, 0.f, 0.f};

    size_t aoff[2];
#pragma unroll
    for (int mi = 0; mi < 2; ++mi) {
        int R = bm + wr * 32 + mi * 16 + lr;
        if (R >= M) R = M - 1;
        aoff[mi] = (size_t)R * K + ko * 8;
    }
    size_t boff[4];
#pragma unroll
    for (int ni = 0; ni < 4; ++ni) {
        int n = wc * 64 + ni * 16 + lr;
        boff[ni] = (size_t)n * K + ko * 8;
    }

#pragma unroll 4
    for (int k0 = 0; k0 < K; k0 += 32) {
        bf16x8 a[2], b[4];
#pragma unroll
        for (int mi = 0; mi < 2; ++mi) {
            if constexpr (AF32) {
                const float* p = (const float*)Ap + aoff[mi] + k0;
                float4 u = *(const float4*)p;
                float4 v = *(const float4*)(p + 4);
                a[mi] = pack_bf8(u, v);
            } else {
                a[mi] = *(const bf16x8*)((const unsigned short*)Ap + aoff[mi] + k0);
            }
        }
#pragma unroll
        for (int ni = 0; ni < 4; ++ni) b[ni] = *(const bf16x8*)(Wt + boff[ni] + k0);
#pragma unroll
        for (int mi = 0; mi < 2; ++mi)
#pragma unroll
            for (int ni = 0; ni < 4; ++ni)
                acc[mi][ni] = __builtin_amdgcn_mfma_f32_16x16x32_bf16(a[mi], b[ni], acc[mi][ni], 0, 0, 0);
    }

    // C/D layout: col = lane&15, row = (lane>>4)*4 + reg
#pragma unroll
    for (int mi = 0; mi < 2; ++mi) {
        int Rb = bm + wr * 32 + mi * 16 + ko * 4;
#pragma unroll
        for (int r = 0; r < 4; ++r) {
            int R = Rb + r;
            if (R < M) {
#pragma unroll
                for (int ni = 0; ni < 4; ++ni) {
                    int C = wc * 64 + ni * 16 + lr;
                    H[(size_t)R * HID + C] = f2bf(acc[mi][ni][r]);
                }
            }
        }
    }
}

// ---------------- CSR gather-aggregate (bf16 in/out, fp32 accum), 8/4/1 unrolled ----------------
__global__ __launch_bounds__(256) void agg_csr_kernel(
    const unsigned int* __restrict__ h32, const int* __restrict__ offs, const int* __restrict__ csrc,
    const float* __restrict__ wgt, const float* __restrict__ dinv, const float* __restrict__ bias,
    unsigned int* __restrict__ xo, int N) {
    const int lane = threadIdx.x & 63;
    const int n = (blockIdx.x * blockDim.x + threadIdx.x) >> 6;
    if (n >= N) return;
    const float d = dinv[n];
    unsigned int sv = h32[(size_t)n * 64 + lane];
    float ax = bf2f((unsigned short)(sv & 0xffff)) * (d * d) + bias[2 * lane + 0];
    float ay = bf2f((unsigned short)(sv >> 16)) * (d * d) + bias[2 * lane + 1];
    int e = offs[n];
    const int e1 = offs[n + 1];

    for (; e + 8 <= e1; e += 8) {
        int r[8];
        float wv[8];
        unsigned int v[8];
#pragma unroll
        for (int j = 0; j < 8; ++j) r[j] = csrc[e + j];
#pragma unroll
        for (int j = 0; j < 8; ++j) wv[j] = wgt[e + j];
#pragma unroll
        for (int j = 0; j < 8; ++j) v[j] = h32[(size_t)r[j] * 64 + lane];
#pragma unroll
        for (int j = 0; j < 8; ++j) {
            ax += bf2f((unsigned short)(v[j] & 0xffff)) * wv[j];
            ay += bf2f((unsigned short)(v[j] >> 16)) * wv[j];
        }
    }
    for (; e + 4 <= e1; e += 4) {
        int r[4];
        float wv[4];
        unsigned int v[4];
#pragma unroll
        for (int j = 0; j < 4; ++j) r[j] = csrc[e + j];
#pragma unroll
        for (int j = 0; j < 4; ++j) wv[j] = wgt[e + j];
#pragma unroll
        for (int j = 0; j < 4; ++j) v[j] = h32[(size_t)r[j] * 64 + lane];
#pragma unroll
        for (int j = 0; j < 4; ++j) {
            ax += bf2f((unsigned short)(v[j] & 0xffff)) * wv[j];
            ay += bf2f((unsigned short)(v[j] >> 16)) * wv[j];
        }
    }
    for (; e < e1; ++e) {
        int r = csrc[e];
        float wv = wgt[e];
        unsigned int v = h32[(size_t)r * 64 + lane];
        ax += bf2f((unsigned short)(v & 0xffff)) * wv;
        ay += bf2f((unsigned short)(v >> 16)) * wv;
    }
    ax = fmaxf(ax, 0.f);
    ay = fmaxf(ay, 0.f);
    xo[(size_t)n * 64 + lane] = (unsigned int)f2bf(ax) | ((unsigned int)f2bf(ay) << 16);
}

// ---------------- head: out[M][40] = [x1|x2|x3] @ Wout + bout  (Wot bf16 [48][384]) ----------------
__global__ __launch_bounds__(256) void head_mfma_kernel(
    const unsigned short* __restrict__ x1, const unsigned short* __restrict__ x2,
    const unsigned short* __restrict__ x3, const unsigned short* __restrict__ Wt,
    const float* __restrict__ bout, float* __restrict__ out, int M) {
    const int tid = threadIdx.x;
    const int lane = tid & 63;
    const int w = tid >> 6;
    const int lr = lane & 15;
    const int ko = lane >> 4;
    const int bm = blockIdx.x * 64;
    int R = bm + w * 16 + lr;
    if (R >= M) R = M - 1;
    const unsigned short* xs[3] = {x1, x2, x3};

    f32x4 acc[3];
#pragma unroll
    for (int i = 0; i < 3; ++i) acc[i] = (f32x4){0.f, 0.f, 0.f, 0.f};

#pragma unroll
    for (int s = 0; s < 3; ++s) {
        const unsigned short* xp = xs[s] + (size_t)R * HID + ko * 8;
#pragma unroll
        for (int c = 0; c < 4; ++c) {
            bf16x8 a = *(const bf16x8*)(xp + c * 32);
#pragma unroll
            for (int ni = 0; ni < 3; ++ni) {
                bf16x8 b = *(const bf16x8*)(Wt + (size_t)(ni * 16 + lr) * 384 + s * 128 + c * 32 + ko * 8);
                acc[ni] = __builtin_amdgcn_mfma_f32_16x16x32_bf16(a, b, acc[ni], 0, 0, 0);
            }
        }
    }

    int Rb = bm + w * 16 + ko * 4;
#pragma unroll
    for (int r = 0; r < 4; ++r) {
        int Ro = Rb + r;
        if (Ro < M) {
#pragma unroll
            for (int ni = 0; ni < 3; ++ni) {
                int C = ni * 16 + lr;
                if (C < NOUT) out[(size_t)Ro * NOUT + C] = acc[ni][r] + bout[C];
            }
        }
    }
}

// ---------------- launch ----------------
static inline size_t align_up(size_t x, size_t a) { return (x + a - 1) / a * a; }

extern "C" void kernel_launch(void* const* d_in, const int* in_sizes, int n_in,
                              void* d_out, int out_size, void* d_ws, size_t ws_size,
                              hipStream_t stream) {
    const float* x    = (const float*)d_in[0];
    const void*  eix  = d_in[1];
    const float* W0   = (const float*)d_in[2];
    const float* b0   = (const float*)d_in[3];
    const float* W1   = (const float*)d_in[4];
    const float* b1   = (const float*)d_in[5];
    const float* W2   = (const float*)d_in[6];
    const float* b2   = (const float*)d_in[7];
    const float* Wout = (const float*)d_in[8];
    const float* bout = (const float*)d_in[9];
    float* out = (float*)d_out;

    const int D = 256;
    const int N = in_sizes[0] / D;        // 50000
    const int E = in_sizes[1] / 2;        // 800000

    // workspace carve-out
    char* w = (char*)d_ws;
    size_t off = 0;
    int* rc = (int*)(w + off);              off = align_up(off + (size_t)2 * E * 4, 256);
    int* deg = (int*)(w + off);             off = align_up(off + (size_t)N * 4, 256);
    float* dinv = (float*)(w + off);        off = align_up(off + (size_t)N * 4, 256);
    int* offs = (int*)(w + off);            off = align_up(off + (size_t)(N + 1) * 4, 256);
    int* cursor = (int*)(w + off);          off = align_up(off + (size_t)N * 4, 256);
    int* bsum = (int*)(w + off);            off = align_up(off + 1024 * 4, 256);
    int* flag = (int*)(w + off);            off = align_up(off + 16, 256);
    int* csrc = (int*)(w + off);            off = align_up(off + (size_t)E * 4, 256);
    float* wgt = (float*)(w + off);         off = align_up(off + (size_t)E * 4, 256);
    unsigned short* h   = (unsigned short*)(w + off); off = align_up(off + (size_t)N * HID * 2, 256);
    unsigned short* x1b = (unsigned short*)(w + off); off = align_up(off + (size_t)N * HID * 2, 256);
    unsigned short* x2b = (unsigned short*)(w + off); off = align_up(off + (size_t)N * HID * 2, 256);
    unsigned short* x3b = (unsigned short*)(w + off); off = align_up(off + (size_t)N * HID * 2, 256);
    unsigned short* W0t = (unsigned short*)(w + off); off = align_up(off + (size_t)HID * 256 * 2, 256);
    unsigned short* W1t = (unsigned short*)(w + off); off = align_up(off + (size_t)HID * HID * 2, 256);
    unsigned short* W2t = (unsigned short*)(w + off); off = align_up(off + (size_t)HID * HID * 2, 256);
    unsigned short* Wot = (unsigned short*)(w + off); off = align_up(off + (size_t)48 * 384 * 2, 256);
    (void)ws_size;

    int* row = rc;
    int* col = rc + E;

    // ---- graph prep ----
    detect_fmt_kernel<<<1, 64, 0, stream>>>((const unsigned int*)eix, flag);
    hipMemsetAsync(deg, 0, (size_t)N * 4, stream);
    convert_kernel<<<(2 * E + 255) / 256, 256, 0, stream>>>(eix, flag, rc, deg, 2 * E);

    const int nb = (N + SCAN_B - 1) / SCAN_B;  // 196 <= 256
    scan1_kernel<<<nb, SCAN_B, 0, stream>>>(deg, offs, bsum, dinv, N);
    scan2_kernel<<<1, SCAN_B, 0, stream>>>(bsum, nb);
    scan3_kernel<<<nb, SCAN_B, 0, stream>>>(offs, bsum, cursor, N, E);
    fill_csr_kernel<<<(E + 255) / 256, 256, 0, stream>>>(row, col, dinv, cursor, csrc, wgt, E);

    // ---- weights to bf16 (transposed) ----
    wt_kernel<<<(HID * 256 + 255) / 256, 256, 0, stream>>>(W0, W0t, 256, HID, HID);
    wt_kernel<<<(HID * HID + 255) / 256, 256, 0, stream>>>(W1, W1t, HID, HID, HID);
    wt_kernel<<<(HID * HID + 255) / 256, 256, 0, stream>>>(W2, W2t, HID, HID, HID);
    wt_kernel<<<(48 * 384 + 255) / 256, 256, 0, stream>>>(Wout, Wot, 384, NOUT, 48);

    const int gGemm = (N + 63) / 64;
    const int gAgg = (N * 64 + 255) / 256;

    // layer 0 (f32 A, converted inline)
    gemm_mfma_kernel<true><<<gGemm, 256, 0, stream>>>(x, W0t, h, N, 256);
    agg_csr_kernel<<<gAgg, 256, 0, stream>>>((const unsigned int*)h, offs, csrc, wgt, dinv, b0, (unsigned int*)x1b, N);
    // layer 1
    gemm_mfma_kernel<false><<<gGemm, 256, 0, stream>>>(x1b, W1t, h, N, HID);
    agg_csr_kernel<<<gAgg, 256, 0, stream>>>((const unsigned int*)h, offs, csrc, wgt, dinv, b1, (unsigned int*)x2b, N);
    // layer 2
    gemm_mfma_kernel<false><<<gGemm, 256, 0, stream>>>(x2b, W2t, h, N, HID);
    agg_csr_kernel<<<gAgg, 256, 0, stream>>>((const unsigned int*)h, offs, csrc, wgt, dinv, b2, (unsigned int*)x3b, N);
    // head
    head_mfma_kernel<<<gGemm, 256, 0, stream>>>(x1b, x2b, x3b, Wot, bout, out, N);
}

// Round 5
// 390.415 us; speedup vs baseline: 6.5109x; 1.0268x over previous
//
#include <hip/hip_runtime.h>

#define HID 128
#define NOUT 40
#define SCAN_B 256

typedef __attribute__((ext_vector_type(8))) short bf16x8;
typedef __attribute__((ext_vector_type(4))) float f32x4;

__device__ inline float bf2f(unsigned int u) {
    unsigned int t = u << 16;
    float f;
    __builtin_memcpy(&f, &t, 4);
    return f;
}
__device__ inline unsigned short f2bf(float f) {
    unsigned int x;
    __builtin_memcpy(&x, &f, 4);
    unsigned int r = (x + 0x7fffu + ((x >> 16) & 1u)) >> 16;  // RNE
    return (unsigned short)r;
}
__device__ inline bf16x8 pack_bf8(float4 u, float4 v) {
    bf16x8 r;
    r[0] = (short)f2bf(u.x); r[1] = (short)f2bf(u.y);
    r[2] = (short)f2bf(u.z); r[3] = (short)f2bf(u.w);
    r[4] = (short)f2bf(v.x); r[5] = (short)f2bf(v.y);
    r[6] = (short)f2bf(v.z); r[7] = (short)f2bf(v.w);
    return r;
}

// ---------------- edge dtype detect ----------------
__global__ void detect_fmt_kernel(const unsigned int* __restrict__ e, int* __restrict__ flag) {
    int t = threadIdx.x;  // one wave
    unsigned int v = e[2 * t + 1];
    unsigned long long ball = __ballot(v == 0u);
    if (t == 0) *flag = (ball == ~0ull) ? 1 : 0;
}

// in-degree count straight from edge_index col half
__global__ void degree_kernel(const void* __restrict__ eix, const int* __restrict__ flag,
                              int* __restrict__ deg, int E) {
    int i = blockIdx.x * blockDim.x + threadIdx.x;
    if (i >= E) return;
    int f = *flag;
    int c = f ? (int)(((const long long*)eix)[(size_t)E + i]) : ((const int*)eix)[(size_t)E + i];
    atomicAdd(&deg[c], 1);
}

// ---------------- exclusive scan (+ fused dinv in pass 1, cursor in pass 3) ----------------
__global__ void scan1_kernel(const int* __restrict__ deg, int* __restrict__ offs,
                             int* __restrict__ bsum, float* __restrict__ dinv, int N) {
    __shared__ int s[SCAN_B];
    int i = blockIdx.x * SCAN_B + threadIdx.x;
    int v = (i < N) ? deg[i] : 0;
    if (i < N) dinv[i] = rsqrtf((float)v + 1.0f);  // +1 self loop
    s[threadIdx.x] = v;
    __syncthreads();
    for (int d = 1; d < SCAN_B; d <<= 1) {
        int t = (threadIdx.x >= d) ? s[threadIdx.x - d] : 0;
        __syncthreads();
        s[threadIdx.x] += t;
        __syncthreads();
    }
    if (i < N) offs[i] = s[threadIdx.x] - v;
    if (threadIdx.x == SCAN_B - 1) bsum[blockIdx.x] = s[SCAN_B - 1];
}

__global__ void scan2_kernel(int* __restrict__ bsum, int nb) {
    __shared__ int s[SCAN_B];
    int v = (threadIdx.x < nb) ? bsum[threadIdx.x] : 0;
    s[threadIdx.x] = v;
    __syncthreads();
    for (int d = 1; d < SCAN_B; d <<= 1) {
        int t = (threadIdx.x >= d) ? s[threadIdx.x - d] : 0;
        __syncthreads();
        s[threadIdx.x] += t;
        __syncthreads();
    }
    if (threadIdx.x < nb) bsum[threadIdx.x] = s[threadIdx.x] - v;
}

__global__ void scan3_kernel(int* __restrict__ offs, const int* __restrict__ bsum,
                             int* __restrict__ cursor, int N, int E) {
    int i = blockIdx.x * SCAN_B + threadIdx.x;
    if (i < N) {
        int v = offs[i] + bsum[blockIdx.x];
        offs[i] = v;
        cursor[i] = v;
    }
    if (blockIdx.x == 0 && threadIdx.x == 0) offs[N] = E;
}

// CSR fill from edge_index directly; packed (src, wgt) single 8B scatter
__global__ void fill_csr_kernel(const void* __restrict__ eix, const int* __restrict__ flag,
                                const float* __restrict__ dinv, int* __restrict__ cursor,
                                int2* __restrict__ pkd, int E) {
    int e = blockIdx.x * blockDim.x + threadIdx.x;
    if (e >= E) return;
    int f = *flag;
    int r, c;
    if (f) {
        r = (int)(((const long long*)eix)[e]);
        c = (int)(((const long long*)eix)[(size_t)E + e]);
    } else {
        r = ((const int*)eix)[e];
        c = ((const int*)eix)[(size_t)E + e];
    }
    int p = atomicAdd(&cursor[c], 1);
    float wv = dinv[r] * dinv[c];
    int2 rec;
    rec.x = r;
    rec.y = __float_as_int(wv);
    pkd[p] = rec;
}

// ---------------- merged weight transpose+convert ----------------
// seg0: W0 [256][128] -> W0t [128][256]; seg1/2: W1,W2 [128][128] -> [128][128];
// seg3: Wout [384][40] -> Wot [48][384] (zero-pad rows 40..47)
__global__ void wt_all_kernel(const float* __restrict__ W0, const float* __restrict__ W1,
                              const float* __restrict__ W2, const float* __restrict__ Wo,
                              unsigned short* __restrict__ W0t, unsigned short* __restrict__ W1t,
                              unsigned short* __restrict__ W2t, unsigned short* __restrict__ Wot) {
    int idx = blockIdx.x * blockDim.x + threadIdx.x;
    const int s0 = 128 * 256, s1 = 128 * 128, s2 = 128 * 128, s3 = 48 * 384;
    if (idx < s0) {
        int n = idx >> 8, k = idx & 255;
        W0t[idx] = f2bf(W0[(size_t)k * 128 + n]);
    } else if ((idx -= s0) < s1) {
        int n = idx >> 7, k = idx & 127;
        W1t[idx] = f2bf(W1[(size_t)k * 128 + n]);
    } else if ((idx -= s1) < s2) {
        int n = idx >> 7, k = idx & 127;
        W2t[idx] = f2bf(W2[(size_t)k * 128 + n]);
    } else if ((idx -= s2) < s3) {
        int n = idx / 384, k = idx - n * 384;
        Wot[idx] = (n < NOUT) ? f2bf(Wo[(size_t)k * NOUT + n]) : (unsigned short)0;
    }
}

// ---------------- MFMA GEMM: H[M][128] = A[M][K] @ W   (Wt bf16 [128][K]) ----------------
// LDS-free: BM=64, 4 waves (2x2), per-wave 32x64, fragments straight from global.
template <bool AF32>
__global__ __launch_bounds__(256) void gemm_mfma_kernel(
    const void* __restrict__ Ap, const unsigned short* __restrict__ Wt,
    unsigned short* __restrict__ H, int M, int K) {
    const int tid = threadIdx.x;
    const int lane = tid & 63;
    const int w = tid >> 6;
    const int wr = w >> 1, wc = w & 1;
    const int lr = lane & 15;
    const int ko = lane >> 4;
    const int bm = blockIdx.x * 64;

    f32x4 acc[2][4];
#pragma unroll
    for (int i = 0; i < 2; ++i)
#pragma unroll
        for (int j = 0; j < 4; ++j) acc[i][j] = (f32x4){0.f, 0.f, 0.f, 0.f};

    size_t aoff[2];
#pragma unroll
    for (int mi = 0; mi < 2; ++mi) {
        int R = bm + wr * 32 + mi * 16 + lr;
        if (R >= M) R = M - 1;
        aoff[mi] = (size_t)R * K + ko * 8;
    }
    size_t boff[4];
#pragma unroll
    for (int ni = 0; ni < 4; ++ni) {
        int n = wc * 64 + ni * 16 + lr;
        boff[ni] = (size_t)n * K + ko * 8;
    }

#pragma unroll 4
    for (int k0 = 0; k0 < K; k0 += 32) {
        bf16x8 a[2], b[4];
#pragma unroll
        for (int mi = 0; mi < 2; ++mi) {
            if constexpr (AF32) {
                const float* p = (const float*)Ap + aoff[mi] + k0;
                float4 u = *(const float4*)p;
                float4 v = *(const float4*)(p + 4);
                a[mi] = pack_bf8(u, v);
            } else {
                a[mi] = *(const bf16x8*)((const unsigned short*)Ap + aoff[mi] + k0);
            }
        }
#pragma unroll
        for (int ni = 0; ni < 4; ++ni) b[ni] = *(const bf16x8*)(Wt + boff[ni] + k0);
#pragma unroll
        for (int mi = 0; mi < 2; ++mi)
#pragma unroll
            for (int ni = 0; ni < 4; ++ni)
                acc[mi][ni] = __builtin_amdgcn_mfma_f32_16x16x32_bf16(a[mi], b[ni], acc[mi][ni], 0, 0, 0);
    }

    // C/D layout: col = lane&15, row = (lane>>4)*4 + reg
#pragma unroll
    for (int mi = 0; mi < 2; ++mi) {
        int Rb = bm + wr * 32 + mi * 16 + ko * 4;
#pragma unroll
        for (int r = 0; r < 4; ++r) {
            int R = Rb + r;
            if (R < M) {
#pragma unroll
                for (int ni = 0; ni < 4; ++ni) {
                    int C = wc * 64 + ni * 16 + lr;
                    H[(size_t)R * HID + C] = f2bf(acc[mi][ni][r]);
                }
            }
        }
    }
}

// ---------------- CSR gather-aggregate (bf16 in/out, fp32 accum), 16/4/1 unrolled ----------------
__global__ __launch_bounds__(256) void agg_csr_kernel(
    const unsigned int* __restrict__ h32, const int* __restrict__ offs,
    const int2* __restrict__ pkd, const float* __restrict__ dinv,
    const float* __restrict__ bias, unsigned int* __restrict__ xo, int N) {
    const int lane = threadIdx.x & 63;
    const int n = (blockIdx.x * blockDim.x + threadIdx.x) >> 6;
    if (n >= N) return;
    const float d = dinv[n];
    unsigned int sv = h32[(size_t)n * 64 + lane];
    float ax = bf2f(sv & 0xffff) * (d * d) + bias[2 * lane + 0];
    float ay = bf2f(sv >> 16) * (d * d) + bias[2 * lane + 1];
    int e = offs[n];
    const int e1 = offs[n + 1];

    for (; e + 16 <= e1; e += 16) {
        int2 pk[16];
        unsigned int v[16];
#pragma unroll
        for (int j = 0; j < 16; ++j) pk[j] = pkd[e + j];
#pragma unroll
        for (int j = 0; j < 16; ++j) v[j] = h32[(size_t)pk[j].x * 64 + lane];
#pragma unroll
        for (int j = 0; j < 16; ++j) {
            float wv = __int_as_float(pk[j].y);
            ax += bf2f(v[j] & 0xffff) * wv;
            ay += bf2f(v[j] >> 16) * wv;
        }
    }
    for (; e + 4 <= e1; e += 4) {
        int2 pk[4];
        unsigned int v[4];
#pragma unroll
        for (int j = 0; j < 4; ++j) pk[j] = pkd[e + j];
#pragma unroll
        for (int j = 0; j < 4; ++j) v[j] = h32[(size_t)pk[j].x * 64 + lane];
#pragma unroll
        for (int j = 0; j < 4; ++j) {
            float wv = __int_as_float(pk[j].y);
            ax += bf2f(v[j] & 0xffff) * wv;
            ay += bf2f(v[j] >> 16) * wv;
        }
    }
    for (; e < e1; ++e) {
        int2 pk = pkd[e];
        unsigned int v = h32[(size_t)pk.x * 64 + lane];
        float wv = __int_as_float(pk.y);
        ax += bf2f(v & 0xffff) * wv;
        ay += bf2f(v >> 16) * wv;
    }
    ax = fmaxf(ax, 0.f);
    ay = fmaxf(ay, 0.f);
    xo[(size_t)n * 64 + lane] = (unsigned int)f2bf(ax) | ((unsigned int)f2bf(ay) << 16);
}

// ---------------- head: out[M][40] = [x1|x2|x3] @ Wout + bout  (Wot bf16 [48][384]) ----------------
__global__ __launch_bounds__(256) void head_mfma_kernel(
    const unsigned short* __restrict__ x1, const unsigned short* __restrict__ x2,
    const unsigned short* __restrict__ x3, const unsigned short* __restrict__ Wt,
    const float* __restrict__ bout, float* __restrict__ out, int M) {
    const int tid = threadIdx.x;
    const int lane = tid & 63;
    const int w = tid >> 6;
    const int lr = lane & 15;
    const int ko = lane >> 4;
    const int bm = blockIdx.x * 64;
    int R = bm + w * 16 + lr;
    if (R >= M) R = M - 1;
    const unsigned short* xs[3] = {x1, x2, x3};

    f32x4 acc[3];
#pragma unroll
    for (int i = 0; i < 3; ++i) acc[i] = (f32x4){0.f, 0.f, 0.f, 0.f};

#pragma unroll
    for (int s = 0; s < 3; ++s) {
        const unsigned short* xp = xs[s] + (size_t)R * HID + ko * 8;
#pragma unroll
        for (int c = 0; c < 4; ++c) {
            bf16x8 a = *(const bf16x8*)(xp + c * 32);
#pragma unroll
            for (int ni = 0; ni < 3; ++ni) {
                bf16x8 b = *(const bf16x8*)(Wt + (size_t)(ni * 16 + lr) * 384 + s * 128 + c * 32 + ko * 8);
                acc[ni] = __builtin_amdgcn_mfma_f32_16x16x32_bf16(a, b, acc[ni], 0, 0, 0);
            }
        }
    }

    int Rb = bm + w * 16 + ko * 4;
#pragma unroll
    for (int r = 0; r < 4; ++r) {
        int Ro = Rb + r;
        if (Ro < M) {
#pragma unroll
            for (int ni = 0; ni < 3; ++ni) {
                int C = ni * 16 + lr;
                if (C < NOUT) out[(size_t)Ro * NOUT + C] = acc[ni][r] + bout[C];
            }
        }
    }
}

// ---------------- launch ----------------
static inline size_t align_up(size_t x, size_t a) { return (x + a - 1) / a * a; }

extern "C" void kernel_launch(void* const* d_in, const int* in_sizes, int n_in,
                              void* d_out, int out_size, void* d_ws, size_t ws_size,
                              hipStream_t stream) {
    const float* x    = (const float*)d_in[0];
    const void*  eix  = d_in[1];
    const float* W0   = (const float*)d_in[2];
    const float* b0   = (const float*)d_in[3];
    const float* W1   = (const float*)d_in[4];
    const float* b1   = (const float*)d_in[5];
    const float* W2   = (const float*)d_in[6];
    const float* b2   = (const float*)d_in[7];
    const float* Wout = (const float*)d_in[8];
    const float* bout = (const float*)d_in[9];
    float* out = (float*)d_out;

    const int D = 256;
    const int N = in_sizes[0] / D;        // 50000
    const int E = in_sizes[1] / 2;        // 800000

    // workspace carve-out
    char* w = (char*)d_ws;
    size_t off = 0;
    int* deg = (int*)(w + off);             off = align_up(off + (size_t)N * 4, 256);
    float* dinv = (float*)(w + off);        off = align_up(off + (size_t)N * 4, 256);
    int* offs = (int*)(w + off);            off = align_up(off + (size_t)(N + 1) * 4, 256);
    int* cursor = (int*)(w + off);          off = align_up(off + (size_t)N * 4, 256);
    int* bsum = (int*)(w + off);            off = align_up(off + 1024 * 4, 256);
    int* flag = (int*)(w + off);            off = align_up(off + 16, 256);
    int2* pkd = (int2*)(w + off);           off = align_up(off + (size_t)E * 8, 256);
    unsigned short* h   = (unsigned short*)(w + off); off = align_up(off + (size_t)N * HID * 2, 256);
    unsigned short* x1b = (unsigned short*)(w + off); off = align_up(off + (size_t)N * HID * 2, 256);
    unsigned short* x2b = (unsigned short*)(w + off); off = align_up(off + (size_t)N * HID * 2, 256);
    unsigned short* x3b = (unsigned short*)(w + off); off = align_up(off + (size_t)N * HID * 2, 256);
    unsigned short* W0t = (unsigned short*)(w + off); off = align_up(off + (size_t)HID * 256 * 2, 256);
    unsigned short* W1t = (unsigned short*)(w + off); off = align_up(off + (size_t)HID * HID * 2, 256);
    unsigned short* W2t = (unsigned short*)(w + off); off = align_up(off + (size_t)HID * HID * 2, 256);
    unsigned short* Wot = (unsigned short*)(w + off); off = align_up(off + (size_t)48 * 384 * 2, 256);
    (void)ws_size;

    // ---- graph prep ----
    detect_fmt_kernel<<<1, 64, 0, stream>>>((const unsigned int*)eix, flag);
    hipMemsetAsync(deg, 0, (size_t)N * 4, stream);
    degree_kernel<<<(E + 255) / 256, 256, 0, stream>>>(eix, flag, deg, E);

    const int nb = (N + SCAN_B - 1) / SCAN_B;  // 196 <= 256
    scan1_kernel<<<nb, SCAN_B, 0, stream>>>(deg, offs, bsum, dinv, N);
    scan2_kernel<<<1, SCAN_B, 0, stream>>>(bsum, nb);
    scan3_kernel<<<nb, SCAN_B, 0, stream>>>(offs, bsum, cursor, N, E);
    fill_csr_kernel<<<(E + 255) / 256, 256, 0, stream>>>(eix, flag, dinv, cursor, pkd, E);

    // ---- weights to bf16 (transposed), one kernel ----
    const int wtTot = 128 * 256 + 128 * 128 + 128 * 128 + 48 * 384;
    wt_all_kernel<<<(wtTot + 255) / 256, 256, 0, stream>>>(W0, W1, W2, Wout, W0t, W1t, W2t, Wot);

    const int gGemm = (N + 63) / 64;
    const int gAgg = (N * 64 + 255) / 256;

    // layer 0 (f32 A, converted inline)
    gemm_mfma_kernel<true><<<gGemm, 256, 0, stream>>>(x, W0t, h, N, 256);
    agg_csr_kernel<<<gAgg, 256, 0, stream>>>((const unsigned int*)h, offs, pkd, dinv, b0, (unsigned int*)x1b, N);
    // layer 1
    gemm_mfma_kernel<false><<<gGemm, 256, 0, stream>>>(x1b, W1t, h, N, HID);
    agg_csr_kernel<<<gAgg, 256, 0, stream>>>((const unsigned int*)h, offs, pkd, dinv, b1, (unsigned int*)x2b, N);
    // layer 2
    gemm_mfma_kernel<false><<<gGemm, 256, 0, stream>>>(x2b, W2t, h, N, HID);
    agg_csr_kernel<<<gAgg, 256, 0, stream>>>((const unsigned int*)h, offs, pkd, dinv, b2, (unsigned int*)x3b, N);
    // head
    head_mfma_kernel<<<gGemm, 256, 0, stream>>>(x1b, x2b, x3b, Wot, bout, out, N);
}